// Round 17
// baseline (171.536 us; speedup 1.0000x reference)
//
#include <hip/hip_runtime.h>

// ---------------------------------------------------------------------------
// SGConv (K=2): out = A^2 (X W^T) + b,  A = D^{-1/2}(Adj_clamped + I)D^{-1/2}
// N=50000, E=800000, T=256, H=128. edge_index arrives as int32.
//
// r17 = r16 + per-node SOURCE-SORTED edge lists (insertion sort in passB).
// Rationale: hops are BW-bound (unroll-4->8 was null); sorting each CSR
// range by src makes all waves sweep z in increasing address order ->
// concurrent gathers cluster in a few-MB band -> XCD L2 catches the reuse
// (each z row ~16 gathers; unsorted they miss to L3/HBM every time).
// Transform kept at r16 (stuck at ~40us across 9 variants; retired).
// ---------------------------------------------------------------------------

typedef __attribute__((ext_vector_type(8))) short short8_t;   // 8 bf16
typedef __attribute__((ext_vector_type(4))) float f32x4_t;    // MFMA acc

constexpr int BK    = 256;   // nodes per bucket
constexpr int CAP   = 8192;  // records per bucket (mean 4096 + 64 sigma)
constexpr int CHUNK = 4096;  // edges per passA block

__device__ inline unsigned short f2bf(float f) {               // RNE f32->bf16
    unsigned int u = __float_as_uint(f);
    return (unsigned short)((u + 0x7fffu + ((u >> 16) & 1u)) >> 16);
}
__device__ inline float bf_lo(unsigned int u) { return __uint_as_float(u << 16); }
__device__ inline float bf_hi(unsigned int u) { return __uint_as_float(u & 0xffff0000u); }

// async 16B/lane global->LDS (wave-uniform LDS base + lane*16)
__device__ inline void async_load16(const void* g, void* l) {
    __builtin_amdgcn_global_load_lds(
        (const __attribute__((address_space(1))) unsigned int*)g,
        (__attribute__((address_space(3))) unsigned int*)l, 16, 0, 0);
}

// ---- zero the bucket tails ----
__global__ __launch_bounds__(256) void k_zero(int* __restrict__ p, int n)
{
    int i = blockIdx.x * 256 + threadIdx.x;
    if (i < n) p[i] = 0;
}

// ---- passA: bucket-bin edges; coalesced appends to bucket storage ----
__global__ __launch_bounds__(256) void k_passA(
    const int* __restrict__ rows, const int* __restrict__ cols,
    const float* __restrict__ ew, int E,
    unsigned int* __restrict__ bwr,   // [NB*CAP]  w<<16|row
    unsigned char* __restrict__ bcl,  // [NB*CAP]  col low byte
    int* __restrict__ tails,          // [NB]
    const float* __restrict__ W, unsigned short* __restrict__ Wbf, int WT)
{
    const int tid = threadIdx.x;
    const int gid = blockIdx.x * 256 + tid;
    if (gid < WT) Wbf[gid] = f2bf(W[gid]);       // fold W->bf16 conversion

    __shared__ unsigned short lcol[CHUNK], lrow[CHUNK], lw[CHUNK];
    __shared__ unsigned short sidx[CHUNK];
    __shared__ int hist[256], lofs[256], fill[256], gbase[256];

    const int e0  = blockIdx.x * CHUNK;
    const int cnt = min(CHUNK, E - e0);
    if (cnt <= 0) return;

    hist[tid] = 0; fill[tid] = 0;
    __syncthreads();

    for (int i = tid; i < cnt; i += 256) {
        const int c = cols[e0 + i];
        const int r = rows[e0 + i];
        float w = ew[e0 + i];
        w = (w > 0.0f) ? w : 1e-7f;              // elu(w)<=0 <=> w<=0
        lcol[i] = (unsigned short)c;
        lrow[i] = (unsigned short)r;
        lw[i]   = f2bf(w);
        atomicAdd(&hist[c >> 8], 1);
    }
    __syncthreads();

    // exclusive scan of hist -> lofs
    {
        const int v = hist[tid];
        lofs[tid] = v;
        __syncthreads();
        for (int off = 1; off < 256; off <<= 1) {
            int t = (tid >= off) ? lofs[tid - off] : 0;
            __syncthreads();
            lofs[tid] += t;
            __syncthreads();
        }
        const int excl = lofs[tid] - v;
        __syncthreads();
        lofs[tid] = excl;
        __syncthreads();
    }

    // rank within block -> sorted index
    for (int i = tid; i < cnt; i += 256) {
        const int b = lcol[i] >> 8;
        const int pos = lofs[b] + atomicAdd(&fill[b], 1);
        sidx[pos] = (unsigned short)i;
    }
    __syncthreads();

    // reserve global space: one atomic per non-empty bucket
    {
        const int h = hist[tid];
        gbase[tid] = (h > 0) ? atomicAdd(&tails[tid], h) : 0;
    }
    __syncthreads();

    // write out in bucket-sorted order (runs of consecutive addresses)
    for (int i = tid; i < cnt; i += 256) {
        const int e = sidx[i];
        const int b = lcol[e] >> 8;
        const int slot = gbase[b] + (i - lofs[b]);
        if (slot < CAP) {                         // overflow guard
            const int addr = b * CAP + slot;
            bwr[addr] = ((unsigned int)lw[e] << 16) | lrow[e];
            bcl[addr] = (unsigned char)(lcol[e] & 255);
        }
    }
}

// ---- passB: per-bucket sort by (dst, src) + dis/starts/ends ----
__global__ __launch_bounds__(256) void k_passB(
    const unsigned int* __restrict__ bwr, const unsigned char* __restrict__ bcl,
    const int* __restrict__ tails,
    unsigned int* __restrict__ meta, int* __restrict__ starts,
    int* __restrict__ ends, float* __restrict__ dis, int N)
{
    const int tid  = threadIdx.x;
    const int b    = blockIdx.x;
    const int base = b * CAP;
    const int cnt  = min(tails[b], CAP);

    __shared__ unsigned int  lwr[CAP];      // 32 KB
    __shared__ unsigned char lcl[CAP];      // 8 KB
    __shared__ unsigned int  srt[CAP];      // 32 KB
    __shared__ int hist[256], offs[256], fill[256];

    hist[tid] = 0; fill[tid] = 0;
    __syncthreads();

    for (int i = tid; i < cnt; i += 256) {
        lwr[i] = bwr[base + i];
        unsigned char c = bcl[base + i];
        lcl[i] = c;
        atomicAdd(&hist[c], 1);
    }
    __syncthreads();

    // exclusive scan of hist -> offs
    {
        const int v = hist[tid];
        offs[tid] = v;
        __syncthreads();
        for (int off = 1; off < 256; off <<= 1) {
            int t = (tid >= off) ? offs[tid - off] : 0;
            __syncthreads();
            offs[tid] += t;
            __syncthreads();
        }
        const int excl = offs[tid] - v;
        __syncthreads();
        offs[tid] = excl;
        __syncthreads();
    }

    // scatter to dst-sorted order (LDS -> LDS)
    for (int i = tid; i < cnt; i += 256) {
        const int c = lcl[i];
        const int pos = offs[c] + atomicAdd(&fill[c], 1);
        srt[pos] = lwr[i];
    }
    __syncthreads();

    // ---- r17: per-node insertion sort of srt[s..t) by SOURCE (low 16b).
    // Order within a CSR range is math-irrelevant; sorted sources give the
    // hop gather stream monotone addresses -> XCD-L2 band locality.
    {
        const int s = offs[tid];
        const int t = s + hist[tid];
        for (int i = s + 1; i < t; ++i) {
            unsigned int key = srt[i];
            unsigned short ks = (unsigned short)(key & 0xffffu);
            int j = i - 1;
            while (j >= s && (unsigned short)(srt[j] & 0xffffu) > ks) {
                srt[j + 1] = srt[j];
                --j;
            }
            srt[j + 1] = key;
        }
    }
    __syncthreads();

    // coalesced meta write (now (dst,src)-sorted)
    for (int i = tid; i < cnt; i += 256) meta[base + i] = srt[i];

    // per-node: dis = rsqrt(1 + sum w), starts/ends
    const int node = b * BK + tid;
    if (node < N) {
        const int s = offs[tid];
        const int t = s + hist[tid];
        float sum = 1.0f;                         // self-loop
        for (int j = s; j < t; ++j) sum += bf_hi(srt[j]);
        dis[node]    = rsqrtf(sum);
        starts[node] = base + s;
        ends[node]   = base + t;
    }
}

// ---- z[r][:] = permuted bf16( dis[r] * (x[r] @ W^T) ) via MFMA ----
__global__ __launch_bounds__(256, 1) void k_transform_mfma(
    const float* __restrict__ x, const unsigned short* __restrict__ Wbf,
    const float* __restrict__ dis, void* __restrict__ z, int N)
{
    constexpr int RB = 32;
    __shared__ float xs[RB][256];       // 32 KB, LINEAR (global_load_lds dest)

    const int tid  = threadIdx.x;
    const int r0   = blockIdx.x * RB;
    const int wave = tid >> 6;
    const int lane = tid & 63;
    const int lr   = lane & 15;     // A-row / D-col within tile
    const int kg   = lane >> 4;     // k-group (8 consecutive k each)
    const int nb   = (wave & 1) * 4;    // n-tile base (col half)
    const int wr0  = (wave >> 1) * 16;  // row offset within block (0 or 16)

    // ---- async stage: wave w stages rows 8w..8w+7, 1 KB per instruction.
#pragma unroll
    for (int r = 0; r < 8; ++r) {
        const int row  = wave * 8 + r;
        const int grow = r0 + row;
        if (grow < N) {
            const char* src = (const char*)(x + (size_t)grow * 256)
                              + ((lane * 16) ^ ((row & 7) << 4));
            async_load16(src, &xs[row][0]);
        } else {
            *(float4*)((char*)&xs[row][0] + lane * 16) =
                make_float4(0.f, 0.f, 0.f, 0.f);
        }
    }

    // ---- W preload + pin (best effort; see r15/r16 notes) ----
    short8_t wf[4][8];
#pragma unroll
    for (int n = 0; n < 4; ++n)
#pragma unroll
        for (int k = 0; k < 8; ++k)
            wf[n][k] = *reinterpret_cast<const short8_t*>(
                Wbf + (size_t)((nb + n) * 16 + lr) * 256 + k * 32 + kg * 8);
#pragma unroll
    for (int n = 0; n < 4; ++n)
#pragma unroll
        for (int k = 0; k < 8; ++k)
            asm volatile("" : "+v"(wf[n][k]));

    __syncthreads();   // drains vmcnt(0): staging + W loads complete

    f32x4_t acc[4];
#pragma unroll
    for (int n = 0; n < 4; ++n) acc[n] = (f32x4_t){0.f, 0.f, 0.f, 0.f};

    const char* xb  = (const char*)&xs[0][0];
    const int   row = wr0 + lr;
    const int   sw  = (row & 7) << 4;

#pragma unroll
    for (int k = 0; k < 8; ++k) {
        const int g  = k * 128 + kg * 32;
        const int a0 = row * 1024 + (g ^ sw);
        const int a1 = row * 1024 + ((g + 16) ^ sw);
        float4 f0 = *(const float4*)(xb + a0);
        float4 f1 = *(const float4*)(xb + a1);
        short8_t af;
        af[0] = (short)f2bf(f0.x); af[1] = (short)f2bf(f0.y);
        af[2] = (short)f2bf(f0.z); af[3] = (short)f2bf(f0.w);
        af[4] = (short)f2bf(f1.x); af[5] = (short)f2bf(f1.y);
        af[6] = (short)f2bf(f1.z); af[7] = (short)f2bf(f1.w);
#pragma unroll
        for (int n = 0; n < 4; ++n)
            acc[n] = __builtin_amdgcn_mfma_f32_16x16x32_bf16(af, wf[n][k],
                                                             acc[n], 0, 0, 0);
    }

    // permuted store: thread's 4 n-values contiguous -> one uint2 per row.
    char* zb = (char*)z;
    float dsc[4];
#pragma unroll
    for (int r = 0; r < 4; ++r) {
        const int orow = r0 + wr0 + kg * 4 + r;
        dsc[r] = (orow < N) ? dis[orow] : 0.f;
    }
#pragma unroll
    for (int r = 0; r < 4; ++r) {
        const int orow = r0 + wr0 + kg * 4 + r;
        if (orow < N) {
            const float s = dsc[r];
            unsigned int lo = (unsigned int)f2bf(s * acc[0][r]) |
                              ((unsigned int)f2bf(s * acc[1][r]) << 16);
            unsigned int hi = (unsigned int)f2bf(s * acc[2][r]) |
                              ((unsigned int)f2bf(s * acc[3][r]) << 16);
            *(uint2*)(zb + (size_t)orow * 256 + (wave & 1) * 128 + lr * 8) =
                make_uint2(lo, hi);
        }
    }
}

// ---- hop: one wave per dst node, unroll-8 independent gathers ----
// Meta now src-sorted per node -> monotone gather addresses (L2 banding).
template <bool FINAL>
__global__ __launch_bounds__(256) void k_hop(
    const int* __restrict__ starts, const int* __restrict__ ends,
    const unsigned int* __restrict__ meta,
    const float* __restrict__ dis, const unsigned int* __restrict__ hin,
    const float* __restrict__ bias, void* __restrict__ hout, int N)
{
    const int wave = threadIdx.x >> 6;
    const int lane = threadIdx.x & 63;
    const int node = blockIdx.x * 4 + wave;
    if (node >= N) return;

    const int s = __builtin_amdgcn_readfirstlane(starts[node]);
    const int t = __builtin_amdgcn_readfirstlane(ends[node]);
    const float d = dis[node];

    unsigned int v = hin[(size_t)node * 64 + lane];
    float ax = bf_lo(v), ay = bf_hi(v);            // self term z[c]

    int j = s;
    for (; j + 8 <= t; j += 8) {
        unsigned int m0 = meta[j],     m1 = meta[j + 1];
        unsigned int m2 = meta[j + 2], m3 = meta[j + 3];
        unsigned int m4 = meta[j + 4], m5 = meta[j + 5];
        unsigned int m6 = meta[j + 6], m7 = meta[j + 7];
        unsigned int u0 = hin[(size_t)(m0 & 0xffffu) * 64 + lane];
        unsigned int u1 = hin[(size_t)(m1 & 0xffffu) * 64 + lane];
        unsigned int u2 = hin[(size_t)(m2 & 0xffffu) * 64 + lane];
        unsigned int u3 = hin[(size_t)(m3 & 0xffffu) * 64 + lane];
        unsigned int u4 = hin[(size_t)(m4 & 0xffffu) * 64 + lane];
        unsigned int u5 = hin[(size_t)(m5 & 0xffffu) * 64 + lane];
        unsigned int u6 = hin[(size_t)(m6 & 0xffffu) * 64 + lane];
        unsigned int u7 = hin[(size_t)(m7 & 0xffffu) * 64 + lane];
        ax += bf_hi(m0) * bf_lo(u0); ay += bf_hi(m0) * bf_hi(u0);
        ax += bf_hi(m1) * bf_lo(u1); ay += bf_hi(m1) * bf_hi(u1);
        ax += bf_hi(m2) * bf_lo(u2); ay += bf_hi(m2) * bf_hi(u2);
        ax += bf_hi(m3) * bf_lo(u3); ay += bf_hi(m3) * bf_hi(u3);
        ax += bf_hi(m4) * bf_lo(u4); ay += bf_hi(m4) * bf_hi(u4);
        ax += bf_hi(m5) * bf_lo(u5); ay += bf_hi(m5) * bf_hi(u5);
        ax += bf_hi(m6) * bf_lo(u6); ay += bf_hi(m6) * bf_hi(u6);
        ax += bf_hi(m7) * bf_lo(u7); ay += bf_hi(m7) * bf_hi(u7);
    }
    for (; j < t; ++j) {
        unsigned int m = meta[j];
        const float w = bf_hi(m);
        unsigned int u = hin[(size_t)(m & 0xffffu) * 64 + lane];
        ax += w * bf_lo(u); ay += w * bf_hi(u);
    }

    if (FINAL) {
        const int c0 = ((lane & 32) ? 64 : 0) + 32 * (lane & 1) +
                       ((lane & 31) >> 1);
        float* orow = (float*)hout + (size_t)node * 128;
        orow[c0]      = d * ax + bias[c0];
        orow[c0 + 16] = d * ay + bias[c0 + 16];
    } else {
        const float d2 = d * d;
        unsigned int p = (unsigned int)f2bf(d2 * ax) |
                         ((unsigned int)f2bf(d2 * ay) << 16);
        reinterpret_cast<unsigned int*>(hout)[(size_t)node * 64 + lane] = p;
    }
}

extern "C" void kernel_launch(void* const* d_in, const int* in_sizes, int n_in,
                              void* d_out, int out_size, void* d_ws, size_t ws_size,
                              hipStream_t stream)
{
    const float* x  = (const float*)d_in[0];
    const int*   ei = (const int*)d_in[1];     // int32 (harness converts)
    const float* ew = (const float*)d_in[2];
    const float* W  = (const float*)d_in[3];
    const float* b  = (const float*)d_in[4];

    const int E  = in_sizes[2];
    const int H  = in_sizes[4];        // 128
    const int T  = in_sizes[3] / H;    // 256
    const int N  = in_sizes[0] / T;    // 50000  (< 65536: 16-bit ids valid)
    const int WT = in_sizes[3];        // 32768
    const int NB = (N + BK - 1) / BK;  // 196 buckets

    const int* rows = ei;              // sources
    const int* cols = ei + E;          // targets (aggregation index)

    // ---- workspace ----
    char* wsb = (char*)d_ws;
    unsigned int*   z    = (unsigned int*)wsb;   wsb += (size_t)N * (H / 2) * 4;  // 12.8 MB
    unsigned int*   z1   = (unsigned int*)wsb;   wsb += (size_t)N * (H / 2) * 4;  // 12.8 MB
    unsigned int*   meta = (unsigned int*)wsb;   wsb += (size_t)NB * CAP * 4;     // 6.4 MB
    unsigned short* Wbf  = (unsigned short*)wsb; wsb += (size_t)WT * 2;           // 64 KB
    float*          dis  = (float*)wsb;          wsb += (size_t)N * 4;
    int*            sta  = (int*)wsb;            wsb += (size_t)N * 4;
    int*            end_ = (int*)wsb;            wsb += (size_t)N * 4;
    int*            tails= (int*)wsb;            wsb += (size_t)NB * 4;
    // bucket staging aliases z1 (dead until hop1 output): bwr 6.4MB + bcl 1.6MB
    unsigned int*   bwr  = z1;                                  // NB*CAP*4
    unsigned char*  bcl  = (unsigned char*)(z1 + (size_t)NB * CAP);

    float* out = (float*)d_out;

    // CSR build: bucket two-pass
    k_zero<<<(NB + 255) / 256, 256, 0, stream>>>(tails, NB);
    {
        const int nblkA = (E + CHUNK - 1) / CHUNK;   // 196 (covers WT too)
        k_passA<<<nblkA, 256, 0, stream>>>(rows, cols, ew, E,
                                           bwr, bcl, tails, W, Wbf, WT);
        k_passB<<<NB, 256, 0, stream>>>(bwr, bcl, tails,
                                        meta, sta, end_, dis, N);
    }

    // transform: z = permuted bf16(dis * (X W^T))
    {
        const int RB = 32;
        k_transform_mfma<<<(N + RB - 1) / RB, 256, 0, stream>>>(
            x, Wbf, dis, z, N);
    }

    // hops (hop1 overwrites z1 -> bucket staging dead by then)
    const int gH = (N + 3) / 4;
    k_hop<false><<<gH, 256, 0, stream>>>(sta, end_, meta, dis, z, nullptr, z1, N);
    k_hop<true ><<<gH, 256, 0, stream>>>(sta, end_, meta, dis, z1, b, out, N);
}

// Round 18
// 137.073 us; speedup vs baseline: 1.2514x; 1.2514x over previous
//
#include <hip/hip_runtime.h>

// ---------------------------------------------------------------------------
// SGConv (K=2): out = A^2 (X W^T) + b,  A = D^{-1/2}(Adj_clamped + I)D^{-1/2}
// N=50000, E=800000, T=256, H=128. edge_index arrives as int32.
//
// r18:
//  - REVERT r17 per-node sort (cost 45us in passB, hop gain ~0 — banding
//    theory refuted: waves are unsynchronized).
//  - hop: masked full-width unroll-8 (clamp idx, zero weight) — kills the
//    serial tail (mean deg 16 -> ~3.5 serial 900cy gathers/wave was ~60%
//    of hop time).
//  - transform: RB=16, 4 waves, 2 n-tiles/wave (16 W frags), 16KB LDS,
//    3125 blocks -> 4-6 resident blocks/CU for inter-block phase overlap.
//    New store permutation: col(2q) = 32*(q>>4)+(q&15), col(2q+1)=+16.
// CSR build: two-pass bucket sort (r8).
// ---------------------------------------------------------------------------

typedef __attribute__((ext_vector_type(8))) short short8_t;   // 8 bf16
typedef __attribute__((ext_vector_type(4))) float f32x4_t;    // MFMA acc

constexpr int BK    = 256;   // nodes per bucket
constexpr int CAP   = 8192;  // records per bucket (mean 4096 + 64 sigma)
constexpr int CHUNK = 4096;  // edges per passA block

__device__ inline unsigned short f2bf(float f) {               // RNE f32->bf16
    unsigned int u = __float_as_uint(f);
    return (unsigned short)((u + 0x7fffu + ((u >> 16) & 1u)) >> 16);
}
__device__ inline float bf_lo(unsigned int u) { return __uint_as_float(u << 16); }
__device__ inline float bf_hi(unsigned int u) { return __uint_as_float(u & 0xffff0000u); }

// async 16B/lane global->LDS (wave-uniform LDS base + lane*16)
__device__ inline void async_load16(const void* g, void* l) {
    __builtin_amdgcn_global_load_lds(
        (const __attribute__((address_space(1))) unsigned int*)g,
        (__attribute__((address_space(3))) unsigned int*)l, 16, 0, 0);
}

// ---- zero the bucket tails ----
__global__ __launch_bounds__(256) void k_zero(int* __restrict__ p, int n)
{
    int i = blockIdx.x * 256 + threadIdx.x;
    if (i < n) p[i] = 0;
}

// ---- passA: bucket-bin edges; coalesced appends to bucket storage ----
__global__ __launch_bounds__(256) void k_passA(
    const int* __restrict__ rows, const int* __restrict__ cols,
    const float* __restrict__ ew, int E,
    unsigned int* __restrict__ bwr,   // [NB*CAP]  w<<16|row
    unsigned char* __restrict__ bcl,  // [NB*CAP]  col low byte
    int* __restrict__ tails,          // [NB]
    const float* __restrict__ W, unsigned short* __restrict__ Wbf, int WT)
{
    const int tid = threadIdx.x;
    const int gid = blockIdx.x * 256 + tid;
    if (gid < WT) Wbf[gid] = f2bf(W[gid]);       // fold W->bf16 conversion

    __shared__ unsigned short lcol[CHUNK], lrow[CHUNK], lw[CHUNK];
    __shared__ unsigned short sidx[CHUNK];
    __shared__ int hist[256], lofs[256], fill[256], gbase[256];

    const int e0  = blockIdx.x * CHUNK;
    const int cnt = min(CHUNK, E - e0);
    if (cnt <= 0) return;

    hist[tid] = 0; fill[tid] = 0;
    __syncthreads();

    for (int i = tid; i < cnt; i += 256) {
        const int c = cols[e0 + i];
        const int r = rows[e0 + i];
        float w = ew[e0 + i];
        w = (w > 0.0f) ? w : 1e-7f;              // elu(w)<=0 <=> w<=0
        lcol[i] = (unsigned short)c;
        lrow[i] = (unsigned short)r;
        lw[i]   = f2bf(w);
        atomicAdd(&hist[c >> 8], 1);
    }
    __syncthreads();

    // exclusive scan of hist -> lofs
    {
        const int v = hist[tid];
        lofs[tid] = v;
        __syncthreads();
        for (int off = 1; off < 256; off <<= 1) {
            int t = (tid >= off) ? lofs[tid - off] : 0;
            __syncthreads();
            lofs[tid] += t;
            __syncthreads();
        }
        const int excl = lofs[tid] - v;
        __syncthreads();
        lofs[tid] = excl;
        __syncthreads();
    }

    // rank within block -> sorted index
    for (int i = tid; i < cnt; i += 256) {
        const int b = lcol[i] >> 8;
        const int pos = lofs[b] + atomicAdd(&fill[b], 1);
        sidx[pos] = (unsigned short)i;
    }
    __syncthreads();

    // reserve global space: one atomic per non-empty bucket
    {
        const int h = hist[tid];
        gbase[tid] = (h > 0) ? atomicAdd(&tails[tid], h) : 0;
    }
    __syncthreads();

    // write out in bucket-sorted order (runs of consecutive addresses)
    for (int i = tid; i < cnt; i += 256) {
        const int e = sidx[i];
        const int b = lcol[e] >> 8;
        const int slot = gbase[b] + (i - lofs[b]);
        if (slot < CAP) {                         // overflow guard
            const int addr = b * CAP + slot;
            bwr[addr] = ((unsigned int)lw[e] << 16) | lrow[e];
            bcl[addr] = (unsigned char)(lcol[e] & 255);
        }
    }
}

// ---- passB: per-bucket LDS sort + dis/starts/ends; coalesced meta write ----
__global__ __launch_bounds__(256) void k_passB(
    const unsigned int* __restrict__ bwr, const unsigned char* __restrict__ bcl,
    const int* __restrict__ tails,
    unsigned int* __restrict__ meta, int* __restrict__ starts,
    int* __restrict__ ends, float* __restrict__ dis, int N)
{
    const int tid  = threadIdx.x;
    const int b    = blockIdx.x;
    const int base = b * CAP;
    const int cnt  = min(tails[b], CAP);

    __shared__ unsigned int  lwr[CAP];      // 32 KB
    __shared__ unsigned char lcl[CAP];      // 8 KB
    __shared__ unsigned int  srt[CAP];      // 32 KB
    __shared__ int hist[256], offs[256], fill[256];

    hist[tid] = 0; fill[tid] = 0;
    __syncthreads();

    for (int i = tid; i < cnt; i += 256) {
        lwr[i] = bwr[base + i];
        unsigned char c = bcl[base + i];
        lcl[i] = c;
        atomicAdd(&hist[c], 1);
    }
    __syncthreads();

    // exclusive scan of hist -> offs
    {
        const int v = hist[tid];
        offs[tid] = v;
        __syncthreads();
        for (int off = 1; off < 256; off <<= 1) {
            int t = (tid >= off) ? offs[tid - off] : 0;
            __syncthreads();
            offs[tid] += t;
            __syncthreads();
        }
        const int excl = offs[tid] - v;
        __syncthreads();
        offs[tid] = excl;
        __syncthreads();
    }

    // scatter to sorted order (LDS -> LDS)
    for (int i = tid; i < cnt; i += 256) {
        const int c = lcl[i];
        const int pos = offs[c] + atomicAdd(&fill[c], 1);
        srt[pos] = lwr[i];
    }
    __syncthreads();

    // coalesced meta write
    for (int i = tid; i < cnt; i += 256) meta[base + i] = srt[i];

    // per-node: dis = rsqrt(1 + sum w), starts/ends
    const int node = b * BK + tid;
    if (node < N) {
        const int s = offs[tid];
        const int t = s + hist[tid];
        float sum = 1.0f;                         // self-loop
        for (int j = s; j < t; ++j) sum += bf_hi(srt[j]);
        dis[node]    = rsqrtf(sum);
        starts[node] = base + s;
        ends[node]   = base + t;
    }
}

// ---- z[r][:] = permuted bf16( dis[r] * (x[r] @ W^T) ) via MFMA ----
// r18: RB=16, 4 waves, 2 n-tiles/wave -> small blocks, inter-block overlap.
__global__ __launch_bounds__(256) void k_transform_mfma(
    const float* __restrict__ x, const unsigned short* __restrict__ Wbf,
    const float* __restrict__ dis, unsigned int* __restrict__ z, int N)
{
    constexpr int RB = 16;
    __shared__ float xs[RB][256];       // 16 KB, LINEAR (global_load_lds dest)

    const int tid  = threadIdx.x;
    const int r0   = blockIdx.x * RB;
    const int wave = tid >> 6;          // 0..3
    const int lane = tid & 63;
    const int lr   = lane & 15;         // A-row / D-col within tile
    const int kg   = lane >> 4;         // k-group (8 consecutive k each)

    // ---- async stage: wave w stages rows 4w..4w+3, 1 KB per instruction.
    // Global source pre-swizzled (lane*16 ^ (row&7)<<4); LDS stays linear.
#pragma unroll
    for (int r = 0; r < 4; ++r) {
        const int row  = wave * 4 + r;
        const int grow = r0 + row;
        if (grow < N) {
            const char* src = (const char*)(x + (size_t)grow * 256)
                              + ((lane * 16) ^ ((row & 7) << 4));
            async_load16(src, &xs[row][0]);
        } else {
            *(float4*)((char*)&xs[row][0] + lane * 16) =
                make_float4(0.f, 0.f, 0.f, 0.f);
        }
    }
    __syncthreads();   // drains vmcnt(0): staging complete

    f32x4_t acc[2];
    acc[0] = (f32x4_t){0.f, 0.f, 0.f, 0.f};
    acc[1] = (f32x4_t){0.f, 0.f, 0.f, 0.f};

    const char* xb = (const char*)&xs[0][0];
    const int   sw = (lr & 7) << 4;

#pragma unroll
    for (int k = 0; k < 8; ++k) {
        // A-frag: row lr, global bytes [g, g+32); LDS[p] = global[p^sw]
        const int g  = k * 128 + kg * 32;
        const int a0 = lr * 1024 + (g ^ sw);
        const int a1 = lr * 1024 + ((g + 16) ^ sw);
        float4 f0 = *(const float4*)(xb + a0);
        float4 f1 = *(const float4*)(xb + a1);
        short8_t af;
        af[0] = (short)f2bf(f0.x); af[1] = (short)f2bf(f0.y);
        af[2] = (short)f2bf(f0.z); af[3] = (short)f2bf(f0.w);
        af[4] = (short)f2bf(f1.x); af[5] = (short)f2bf(f1.y);
        af[6] = (short)f2bf(f1.z); af[7] = (short)f2bf(f1.w);
#pragma unroll
        for (int n = 0; n < 2; ++n) {
            const short8_t bf = *reinterpret_cast<const short8_t*>(
                Wbf + (size_t)((2 * wave + n) * 16 + lr) * 256 + k * 32 + kg * 8);
            acc[n] = __builtin_amdgcn_mfma_f32_16x16x32_bf16(af, bf,
                                                             acc[n], 0, 0, 0);
        }
    }

    // permuted store: thread's 2 n-values -> one u32 at index wave*16+lr.
    // col(2q) = 32*(q>>4) + (q&15); col(2q+1) = col(2q)+16  [q = u32 index]
    float dsc[4];
#pragma unroll
    for (int r = 0; r < 4; ++r) {
        const int orow = r0 + kg * 4 + r;
        dsc[r] = (orow < N) ? dis[orow] : 0.f;
    }
#pragma unroll
    for (int r = 0; r < 4; ++r) {
        const int orow = r0 + kg * 4 + r;       // D row = kg*4 + reg
        if (orow < N) {
            const float s = dsc[r];
            unsigned int p = (unsigned int)f2bf(s * acc[0][r]) |
                             ((unsigned int)f2bf(s * acc[1][r]) << 16);
            z[(size_t)orow * 64 + wave * 16 + lr] = p;
        }
    }
}

// ---- hop: one wave per dst node, MASKED unroll-8 (no serial tail) ----
// Works in permuted-column space (elementwise). FINAL unwinds:
// q=lane: c0 = 32*(lane>>4) + (lane&15); shorts 2q->c0, 2q+1->c0+16.
template <bool FINAL>
__global__ __launch_bounds__(256) void k_hop(
    const int* __restrict__ starts, const int* __restrict__ ends,
    const unsigned int* __restrict__ meta,
    const float* __restrict__ dis, const unsigned int* __restrict__ hin,
    const float* __restrict__ bias, void* __restrict__ hout, int N)
{
    const int wave = threadIdx.x >> 6;
    const int lane = threadIdx.x & 63;
    const int node = blockIdx.x * 4 + wave;
    if (node >= N) return;

    const int s = __builtin_amdgcn_readfirstlane(starts[node]);
    const int t = __builtin_amdgcn_readfirstlane(ends[node]);
    const float d = dis[node];

    unsigned int v = hin[(size_t)node * 64 + lane];
    float ax = bf_lo(v), ay = bf_hi(v);            // self term z[c]

    for (int j = s; j < t; j += 8) {
        unsigned int mm[8];
        float        ww[8];
#pragma unroll
        for (int u = 0; u < 8; ++u) {
            const int jj = j + u;
            mm[u] = meta[(jj < t) ? jj : (t - 1)];   // clamp (t>s here)
            ww[u] = (jj < t) ? bf_hi(mm[u]) : 0.0f;  // mask OOB weight
        }
        unsigned int uu[8];
#pragma unroll
        for (int u = 0; u < 8; ++u)
            uu[u] = hin[(size_t)(mm[u] & 0xffffu) * 64 + lane];
#pragma unroll
        for (int u = 0; u < 8; ++u) {
            ax += ww[u] * bf_lo(uu[u]);
            ay += ww[u] * bf_hi(uu[u]);
        }
    }

    if (FINAL) {
        const int c0 = 32 * (lane >> 4) + (lane & 15);
        float* orow = (float*)hout + (size_t)node * 128;
        orow[c0]      = d * ax + bias[c0];
        orow[c0 + 16] = d * ay + bias[c0 + 16];
    } else {
        const float d2 = d * d;
        unsigned int p = (unsigned int)f2bf(d2 * ax) |
                         ((unsigned int)f2bf(d2 * ay) << 16);
        reinterpret_cast<unsigned int*>(hout)[(size_t)node * 64 + lane] = p;
    }
}

extern "C" void kernel_launch(void* const* d_in, const int* in_sizes, int n_in,
                              void* d_out, int out_size, void* d_ws, size_t ws_size,
                              hipStream_t stream)
{
    const float* x  = (const float*)d_in[0];
    const int*   ei = (const int*)d_in[1];     // int32 (harness converts)
    const float* ew = (const float*)d_in[2];
    const float* W  = (const float*)d_in[3];
    const float* b  = (const float*)d_in[4];

    const int E  = in_sizes[2];
    const int H  = in_sizes[4];        // 128
    const int T  = in_sizes[3] / H;    // 256
    const int N  = in_sizes[0] / T;    // 50000  (< 65536: 16-bit ids valid)
    const int WT = in_sizes[3];        // 32768
    const int NB = (N + BK - 1) / BK;  // 196 buckets

    const int* rows = ei;              // sources
    const int* cols = ei + E;          // targets (aggregation index)

    // ---- workspace ----
    char* wsb = (char*)d_ws;
    unsigned int*   z    = (unsigned int*)wsb;   wsb += (size_t)N * (H / 2) * 4;  // 12.8 MB
    unsigned int*   z1   = (unsigned int*)wsb;   wsb += (size_t)N * (H / 2) * 4;  // 12.8 MB
    unsigned int*   meta = (unsigned int*)wsb;   wsb += (size_t)NB * CAP * 4;     // 6.4 MB
    unsigned short* Wbf  = (unsigned short*)wsb; wsb += (size_t)WT * 2;           // 64 KB
    float*          dis  = (float*)wsb;          wsb += (size_t)N * 4;
    int*            sta  = (int*)wsb;            wsb += (size_t)N * 4;
    int*            end_ = (int*)wsb;            wsb += (size_t)N * 4;
    int*            tails= (int*)wsb;            wsb += (size_t)NB * 4;
    // bucket staging aliases z1 (dead until hop1 output): bwr 6.4MB + bcl 1.6MB
    unsigned int*   bwr  = z1;                                  // NB*CAP*4
    unsigned char*  bcl  = (unsigned char*)(z1 + (size_t)NB * CAP);

    float* out = (float*)d_out;

    // CSR build: bucket two-pass
    k_zero<<<(NB + 255) / 256, 256, 0, stream>>>(tails, NB);
    {
        const int nblkA = (E + CHUNK - 1) / CHUNK;   // 196 (covers WT too)
        k_passA<<<nblkA, 256, 0, stream>>>(rows, cols, ew, E,
                                           bwr, bcl, tails, W, Wbf, WT);
        k_passB<<<NB, 256, 0, stream>>>(bwr, bcl, tails,
                                        meta, sta, end_, dis, N);
    }

    // transform: z = permuted bf16(dis * (X W^T))
    {
        const int RB = 16;
        k_transform_mfma<<<(N + RB - 1) / RB, 256, 0, stream>>>(
            x, Wbf, dis, z, N);
    }

    // hops (hop1 overwrites z1 -> bucket staging dead by then)
    const int gH = (N + 3) / 4;
    k_hop<false><<<gH, 256, 0, stream>>>(sta, end_, meta, dis, z, nullptr, z1, N);
    k_hop<true ><<<gH, 256, 0, stream>>>(sta, end_, meta, dis, z1, b, out, N);
}

// Round 19
// 121.734 us; speedup vs baseline: 1.4091x; 1.1260x over previous
//
#include <hip/hip_runtime.h>

// ---------------------------------------------------------------------------
// SGConv (K=2): out = A^2 (X W^T) + b,  A = D^{-1/2}(Adj_clamped + I)D^{-1/2}
// N=50000, E=800000, T=256, H=128. edge_index arrives as int32.
//
// r19: transform TRANSPOSED: y^T = W x^T. Wave holds a FIXED 16-row W tile
// -> only 8 distinct W-frag addresses per wave (CSE'd + held in 32 VGPR,
// reused across x-tiles). k-loop = pure ds_read + MFMA (m97 pattern).
// All 10 prior variants streamed W per-(n,k) from L2 inside the loop.
// D-layout bonus: lane holds 4 CONSECUTIVE features of one node -> natural
// z layout, uint2 store; hop2 unwind = coalesced float2 (r7 form).
// Hops: exact unroll-8 + ONE masked tail batch (not r18's all-masked).
// CSR build: two-pass bucket sort (r8).
// ---------------------------------------------------------------------------

typedef __attribute__((ext_vector_type(8))) short short8_t;   // 8 bf16
typedef __attribute__((ext_vector_type(4))) float f32x4_t;    // MFMA acc

constexpr int BK    = 256;   // nodes per bucket
constexpr int CAP   = 8192;  // records per bucket (mean 4096 + 64 sigma)
constexpr int CHUNK = 4096;  // edges per passA block

__device__ inline unsigned short f2bf(float f) {               // RNE f32->bf16
    unsigned int u = __float_as_uint(f);
    return (unsigned short)((u + 0x7fffu + ((u >> 16) & 1u)) >> 16);
}
__device__ inline float bf_lo(unsigned int u) { return __uint_as_float(u << 16); }
__device__ inline float bf_hi(unsigned int u) { return __uint_as_float(u & 0xffff0000u); }

// async 16B/lane global->LDS (wave-uniform LDS base + lane*16)
__device__ inline void async_load16(const void* g, void* l) {
    __builtin_amdgcn_global_load_lds(
        (const __attribute__((address_space(1))) unsigned int*)g,
        (__attribute__((address_space(3))) unsigned int*)l, 16, 0, 0);
}

// ---- zero the bucket tails ----
__global__ __launch_bounds__(256) void k_zero(int* __restrict__ p, int n)
{
    int i = blockIdx.x * 256 + threadIdx.x;
    if (i < n) p[i] = 0;
}

// ---- passA: bucket-bin edges; coalesced appends to bucket storage ----
__global__ __launch_bounds__(256) void k_passA(
    const int* __restrict__ rows, const int* __restrict__ cols,
    const float* __restrict__ ew, int E,
    unsigned int* __restrict__ bwr,   // [NB*CAP]  w<<16|row
    unsigned char* __restrict__ bcl,  // [NB*CAP]  col low byte
    int* __restrict__ tails,          // [NB]
    const float* __restrict__ W, unsigned short* __restrict__ Wbf, int WT)
{
    const int tid = threadIdx.x;
    const int gid = blockIdx.x * 256 + tid;
    if (gid < WT) Wbf[gid] = f2bf(W[gid]);       // fold W->bf16 conversion

    __shared__ unsigned short lcol[CHUNK], lrow[CHUNK], lw[CHUNK];
    __shared__ unsigned short sidx[CHUNK];
    __shared__ int hist[256], lofs[256], fill[256], gbase[256];

    const int e0  = blockIdx.x * CHUNK;
    const int cnt = min(CHUNK, E - e0);
    if (cnt <= 0) return;

    hist[tid] = 0; fill[tid] = 0;
    __syncthreads();

    for (int i = tid; i < cnt; i += 256) {
        const int c = cols[e0 + i];
        const int r = rows[e0 + i];
        float w = ew[e0 + i];
        w = (w > 0.0f) ? w : 1e-7f;              // elu(w)<=0 <=> w<=0
        lcol[i] = (unsigned short)c;
        lrow[i] = (unsigned short)r;
        lw[i]   = f2bf(w);
        atomicAdd(&hist[c >> 8], 1);
    }
    __syncthreads();

    // exclusive scan of hist -> lofs
    {
        const int v = hist[tid];
        lofs[tid] = v;
        __syncthreads();
        for (int off = 1; off < 256; off <<= 1) {
            int t = (tid >= off) ? lofs[tid - off] : 0;
            __syncthreads();
            lofs[tid] += t;
            __syncthreads();
        }
        const int excl = lofs[tid] - v;
        __syncthreads();
        lofs[tid] = excl;
        __syncthreads();
    }

    // rank within block -> sorted index
    for (int i = tid; i < cnt; i += 256) {
        const int b = lcol[i] >> 8;
        const int pos = lofs[b] + atomicAdd(&fill[b], 1);
        sidx[pos] = (unsigned short)i;
    }
    __syncthreads();

    // reserve global space: one atomic per non-empty bucket
    {
        const int h = hist[tid];
        gbase[tid] = (h > 0) ? atomicAdd(&tails[tid], h) : 0;
    }
    __syncthreads();

    // write out in bucket-sorted order (runs of consecutive addresses)
    for (int i = tid; i < cnt; i += 256) {
        const int e = sidx[i];
        const int b = lcol[e] >> 8;
        const int slot = gbase[b] + (i - lofs[b]);
        if (slot < CAP) {                         // overflow guard
            const int addr = b * CAP + slot;
            bwr[addr] = ((unsigned int)lw[e] << 16) | lrow[e];
            bcl[addr] = (unsigned char)(lcol[e] & 255);
        }
    }
}

// ---- passB: per-bucket LDS sort + dis/starts/ends; coalesced meta write ----
__global__ __launch_bounds__(256) void k_passB(
    const unsigned int* __restrict__ bwr, const unsigned char* __restrict__ bcl,
    const int* __restrict__ tails,
    unsigned int* __restrict__ meta, int* __restrict__ starts,
    int* __restrict__ ends, float* __restrict__ dis, int N)
{
    const int tid  = threadIdx.x;
    const int b    = blockIdx.x;
    const int base = b * CAP;
    const int cnt  = min(tails[b], CAP);

    __shared__ unsigned int  lwr[CAP];      // 32 KB
    __shared__ unsigned char lcl[CAP];      // 8 KB
    __shared__ unsigned int  srt[CAP];      // 32 KB
    __shared__ int hist[256], offs[256], fill[256];

    hist[tid] = 0; fill[tid] = 0;
    __syncthreads();

    for (int i = tid; i < cnt; i += 256) {
        lwr[i] = bwr[base + i];
        unsigned char c = bcl[base + i];
        lcl[i] = c;
        atomicAdd(&hist[c], 1);
    }
    __syncthreads();

    // exclusive scan of hist -> offs
    {
        const int v = hist[tid];
        offs[tid] = v;
        __syncthreads();
        for (int off = 1; off < 256; off <<= 1) {
            int t = (tid >= off) ? offs[tid - off] : 0;
            __syncthreads();
            offs[tid] += t;
            __syncthreads();
        }
        const int excl = offs[tid] - v;
        __syncthreads();
        offs[tid] = excl;
        __syncthreads();
    }

    // scatter to sorted order (LDS -> LDS)
    for (int i = tid; i < cnt; i += 256) {
        const int c = lcl[i];
        const int pos = offs[c] + atomicAdd(&fill[c], 1);
        srt[pos] = lwr[i];
    }
    __syncthreads();

    // coalesced meta write
    for (int i = tid; i < cnt; i += 256) meta[base + i] = srt[i];

    // per-node: dis = rsqrt(1 + sum w), starts/ends
    const int node = b * BK + tid;
    if (node < N) {
        const int s = offs[tid];
        const int t = s + hist[tid];
        float sum = 1.0f;                         // self-loop
        for (int j = s; j < t; ++j) sum += bf_hi(srt[j]);
        dis[node]    = rsqrtf(sum);
        starts[node] = base + s;
        ends[node]   = base + t;
    }
}

// ---- z[n][:] = bf16( dis[n] * (x[n] @ W^T) ), NATURAL layout, via y^T=Wx^T
// Wave w: fixed W rows [hb*64 + w*16, +16); iterates 2 x-tiles of 16 rows.
// A = W-frag (8 distinct addrs/wave, held in VGPR); B = x-frag from LDS.
__global__ __launch_bounds__(256) void k_transform_mfma(
    const float* __restrict__ x, const unsigned short* __restrict__ Wbf,
    const float* __restrict__ dis, unsigned int* __restrict__ z, int N)
{
    constexpr int RB = 32;
    __shared__ float xs[RB][256];       // 32 KB, LINEAR (global_load_lds dest)

    const int tid  = threadIdx.x;
    const int r0   = blockIdx.x * RB;
    const int hb   = blockIdx.y;        // 0/1: feature half (64 each)
    const int wave = tid >> 6;          // 0..3
    const int lane = tid & 63;
    const int lr   = lane & 15;
    const int kg   = lane >> 4;         // k-group (8 consecutive k each)
    const int wrow = hb * 64 + wave * 16 + lr;   // this lane's W row (A-row)

    // ---- async stage: wave w stages rows 8w..8w+7, 1 KB per instruction.
    // Global source pre-swizzled (lane*16 ^ (row&7)<<4); LDS stays linear.
#pragma unroll
    for (int r = 0; r < 8; ++r) {
        const int row  = wave * 8 + r;
        const int grow = r0 + row;
        if (grow < N) {
            const char* src = (const char*)(x + (size_t)grow * 256)
                              + ((lane * 16) ^ ((row & 7) << 4));
            async_load16(src, &xs[row][0]);
        } else {
            *(float4*)((char*)&xs[row][0] + lane * 16) =
                make_float4(0.f, 0.f, 0.f, 0.f);
        }
    }

    // ---- W frags: 8 distinct addresses for the whole wave lifetime ----
    short8_t wf[8];
#pragma unroll
    for (int k = 0; k < 8; ++k)
        wf[k] = *reinterpret_cast<const short8_t*>(
            Wbf + (size_t)wrow * 256 + k * 32 + kg * 8);

    __syncthreads();   // drains vmcnt(0): staging (+W) complete

    const char* xb = (const char*)&xs[0][0];

#pragma unroll
    for (int xt = 0; xt < 2; ++xt) {
        f32x4_t acc = (f32x4_t){0.f, 0.f, 0.f, 0.f};
        const int xrow = xt * 16 + lr;          // B-col (node within block)
        const int sw   = (xrow & 7) << 4;
#pragma unroll
        for (int k = 0; k < 8; ++k) {
            // B-frag: x[xrow][k*32+kg*8 .. +8) ; LDS[p] = global[p^sw]
            const int g  = k * 128 + kg * 32;
            const int a0 = xrow * 1024 + (g ^ sw);
            const int a1 = xrow * 1024 + ((g + 16) ^ sw);
            float4 f0 = *(const float4*)(xb + a0);
            float4 f1 = *(const float4*)(xb + a1);
            short8_t bf;
            bf[0] = (short)f2bf(f0.x); bf[1] = (short)f2bf(f0.y);
            bf[2] = (short)f2bf(f0.z); bf[3] = (short)f2bf(f0.w);
            bf[4] = (short)f2bf(f1.x); bf[5] = (short)f2bf(f1.y);
            bf[6] = (short)f2bf(f1.z); bf[7] = (short)f2bf(f1.w);
            acc = __builtin_amdgcn_mfma_f32_16x16x32_bf16(wf[k], bf, acc, 0, 0, 0);
        }
        // D: col(lane&15) = node, row(kg*4+r) = feature -> lane holds
        // 4 CONSECUTIVE features [hb*64+wave*16+kg*4, +4) of node r0+xrow.
        const int node = r0 + xrow;
        if (node < N) {
            const float d = dis[node];
            unsigned int lo = (unsigned int)f2bf(d * acc[0]) |
                              ((unsigned int)f2bf(d * acc[1]) << 16);
            unsigned int hi = (unsigned int)f2bf(d * acc[2]) |
                              ((unsigned int)f2bf(d * acc[3]) << 16);
            // u32 index = feature/2 = hb*32 + wave*8 + kg*2
            *(uint2*)(&z[(size_t)node * 64 + hb * 32 + wave * 8 + kg * 2]) =
                make_uint2(lo, hi);
        }
    }
}

// ---- hop: one wave per dst node; exact unroll-8 + ONE masked tail batch ----
// z natural layout: u32 q holds features {2q, 2q+1}. FINAL: float2 store.
template <bool FINAL>
__global__ __launch_bounds__(256) void k_hop(
    const int* __restrict__ starts, const int* __restrict__ ends,
    const unsigned int* __restrict__ meta,
    const float* __restrict__ dis, const unsigned int* __restrict__ hin,
    const float* __restrict__ bias, void* __restrict__ hout, int N)
{
    const int wave = threadIdx.x >> 6;
    const int lane = threadIdx.x & 63;
    const int node = blockIdx.x * 4 + wave;
    if (node >= N) return;

    const int s = __builtin_amdgcn_readfirstlane(starts[node]);
    const int t = __builtin_amdgcn_readfirstlane(ends[node]);
    const float d = dis[node];

    unsigned int v = hin[(size_t)node * 64 + lane];
    float ax = bf_lo(v), ay = bf_hi(v);            // self term z[c]

    int j = s;
    for (; j + 8 <= t; j += 8) {
        unsigned int m0 = meta[j],     m1 = meta[j + 1];
        unsigned int m2 = meta[j + 2], m3 = meta[j + 3];
        unsigned int m4 = meta[j + 4], m5 = meta[j + 5];
        unsigned int m6 = meta[j + 6], m7 = meta[j + 7];
        unsigned int u0 = hin[(size_t)(m0 & 0xffffu) * 64 + lane];
        unsigned int u1 = hin[(size_t)(m1 & 0xffffu) * 64 + lane];
        unsigned int u2 = hin[(size_t)(m2 & 0xffffu) * 64 + lane];
        unsigned int u3 = hin[(size_t)(m3 & 0xffffu) * 64 + lane];
        unsigned int u4 = hin[(size_t)(m4 & 0xffffu) * 64 + lane];
        unsigned int u5 = hin[(size_t)(m5 & 0xffffu) * 64 + lane];
        unsigned int u6 = hin[(size_t)(m6 & 0xffffu) * 64 + lane];
        unsigned int u7 = hin[(size_t)(m7 & 0xffffu) * 64 + lane];
        ax += bf_hi(m0) * bf_lo(u0); ay += bf_hi(m0) * bf_hi(u0);
        ax += bf_hi(m1) * bf_lo(u1); ay += bf_hi(m1) * bf_hi(u1);
        ax += bf_hi(m2) * bf_lo(u2); ay += bf_hi(m2) * bf_hi(u2);
        ax += bf_hi(m3) * bf_lo(u3); ay += bf_hi(m3) * bf_hi(u3);
        ax += bf_hi(m4) * bf_lo(u4); ay += bf_hi(m4) * bf_hi(u4);
        ax += bf_hi(m5) * bf_lo(u5); ay += bf_hi(m5) * bf_hi(u5);
        ax += bf_hi(m6) * bf_lo(u6); ay += bf_hi(m6) * bf_hi(u6);
        ax += bf_hi(m7) * bf_lo(u7); ay += bf_hi(m7) * bf_hi(u7);
    }
    if (j < t) {                          // remainder: ONE masked batch
        unsigned int mm[8];
        float        ww[8];
#pragma unroll
        for (int u = 0; u < 8; ++u) {
            const int jj = j + u;
            mm[u] = meta[(jj < t) ? jj : (t - 1)];
            ww[u] = (jj < t) ? bf_hi(mm[u]) : 0.0f;
        }
        unsigned int uu[8];
#pragma unroll
        for (int u = 0; u < 8; ++u)
            uu[u] = hin[(size_t)(mm[u] & 0xffffu) * 64 + lane];
#pragma unroll
        for (int u = 0; u < 8; ++u) {
            ax += ww[u] * bf_lo(uu[u]);
            ay += ww[u] * bf_hi(uu[u]);
        }
    }

    if (FINAL) {
        float2 bv = reinterpret_cast<const float2*>(bias)[lane];
        float2 o; o.x = d * ax + bv.x; o.y = d * ay + bv.y;
        reinterpret_cast<float2*>(hout)[(size_t)node * 64 + lane] = o;
    } else {
        const float d2 = d * d;
        unsigned int p = (unsigned int)f2bf(d2 * ax) |
                         ((unsigned int)f2bf(d2 * ay) << 16);
        reinterpret_cast<unsigned int*>(hout)[(size_t)node * 64 + lane] = p;
    }
}

extern "C" void kernel_launch(void* const* d_in, const int* in_sizes, int n_in,
                              void* d_out, int out_size, void* d_ws, size_t ws_size,
                              hipStream_t stream)
{
    const float* x  = (const float*)d_in[0];
    const int*   ei = (const int*)d_in[1];     // int32 (harness converts)
    const float* ew = (const float*)d_in[2];
    const float* W  = (const float*)d_in[3];
    const float* b  = (const float*)d_in[4];

    const int E  = in_sizes[2];
    const int H  = in_sizes[4];        // 128
    const int T  = in_sizes[3] / H;    // 256
    const int N  = in_sizes[0] / T;    // 50000  (< 65536: 16-bit ids valid)
    const int WT = in_sizes[3];        // 32768
    const int NB = (N + BK - 1) / BK;  // 196 buckets

    const int* rows = ei;              // sources
    const int* cols = ei + E;          // targets (aggregation index)

    // ---- workspace ----
    char* wsb = (char*)d_ws;
    unsigned int*   z    = (unsigned int*)wsb;   wsb += (size_t)N * (H / 2) * 4;  // 12.8 MB
    unsigned int*   z1   = (unsigned int*)wsb;   wsb += (size_t)N * (H / 2) * 4;  // 12.8 MB
    unsigned int*   meta = (unsigned int*)wsb;   wsb += (size_t)NB * CAP * 4;     // 6.4 MB
    unsigned short* Wbf  = (unsigned short*)wsb; wsb += (size_t)WT * 2;           // 64 KB
    float*          dis  = (float*)wsb;          wsb += (size_t)N * 4;
    int*            sta  = (int*)wsb;            wsb += (size_t)N * 4;
    int*            end_ = (int*)wsb;            wsb += (size_t)N * 4;
    int*            tails= (int*)wsb;            wsb += (size_t)NB * 4;
    // bucket staging aliases z1 (dead until hop1 output): bwr 6.4MB + bcl 1.6MB
    unsigned int*   bwr  = z1;                                  // NB*CAP*4
    unsigned char*  bcl  = (unsigned char*)(z1 + (size_t)NB * CAP);

    float* out = (float*)d_out;

    // CSR build: bucket two-pass
    k_zero<<<(NB + 255) / 256, 256, 0, stream>>>(tails, NB);
    {
        const int nblkA = (E + CHUNK - 1) / CHUNK;   // 196 (covers WT too)
        k_passA<<<nblkA, 256, 0, stream>>>(rows, cols, ew, E,
                                           bwr, bcl, tails, W, Wbf, WT);
        k_passB<<<NB, 256, 0, stream>>>(bwr, bcl, tails,
                                        meta, sta, end_, dis, N);
    }

    // transform: z = bf16(dis * (X W^T)), natural layout, y^T = W x^T
    {
        const int RB = 32;
        dim3 grid((N + RB - 1) / RB, 2);
        k_transform_mfma<<<grid, 256, 0, stream>>>(x, Wbf, dis, z, N);
    }

    // hops (hop1 overwrites z1 -> bucket staging dead by then)
    const int gH = (N + 3) / 4;
    k_hop<false><<<gH, 256, 0, stream>>>(sta, end_, meta, dis, z, nullptr, z1, N);
    k_hop<true ><<<gH, 256, 0, stream>>>(sta, end_, meta, dis, z1, b, out, N);
}

// Round 20
// 120.857 us; speedup vs baseline: 1.4193x; 1.0073x over previous
//
#include <hip/hip_runtime.h>

// ---------------------------------------------------------------------------
// SGConv (K=2): out = A^2 (X W^T) + b,  A = D^{-1/2}(Adj_clamped + I)D^{-1/2}
// N=50000, E=800000, T=256, H=128. edge_index arrives as int32.
//
// r20 = r19 + hop MLP deepened to 16 outstanding gathers (16-batch loop,
// dual accumulators to break FMA chains) + 8-exact + one masked-8 tail.
// r19 transform (y^T = W x^T, W held in 8 wave-invariant VGPR frags) kept.
// CSR build: two-pass bucket sort (r8).
// ---------------------------------------------------------------------------

typedef __attribute__((ext_vector_type(8))) short short8_t;   // 8 bf16
typedef __attribute__((ext_vector_type(4))) float f32x4_t;    // MFMA acc

constexpr int BK    = 256;   // nodes per bucket
constexpr int CAP   = 8192;  // records per bucket (mean 4096 + 64 sigma)
constexpr int CHUNK = 4096;  // edges per passA block

__device__ inline unsigned short f2bf(float f) {               // RNE f32->bf16
    unsigned int u = __float_as_uint(f);
    return (unsigned short)((u + 0x7fffu + ((u >> 16) & 1u)) >> 16);
}
__device__ inline float bf_lo(unsigned int u) { return __uint_as_float(u << 16); }
__device__ inline float bf_hi(unsigned int u) { return __uint_as_float(u & 0xffff0000u); }

// async 16B/lane global->LDS (wave-uniform LDS base + lane*16)
__device__ inline void async_load16(const void* g, void* l) {
    __builtin_amdgcn_global_load_lds(
        (const __attribute__((address_space(1))) unsigned int*)g,
        (__attribute__((address_space(3))) unsigned int*)l, 16, 0, 0);
}

// ---- zero the bucket tails ----
__global__ __launch_bounds__(256) void k_zero(int* __restrict__ p, int n)
{
    int i = blockIdx.x * 256 + threadIdx.x;
    if (i < n) p[i] = 0;
}

// ---- passA: bucket-bin edges; coalesced appends to bucket storage ----
__global__ __launch_bounds__(256) void k_passA(
    const int* __restrict__ rows, const int* __restrict__ cols,
    const float* __restrict__ ew, int E,
    unsigned int* __restrict__ bwr,   // [NB*CAP]  w<<16|row
    unsigned char* __restrict__ bcl,  // [NB*CAP]  col low byte
    int* __restrict__ tails,          // [NB]
    const float* __restrict__ W, unsigned short* __restrict__ Wbf, int WT)
{
    const int tid = threadIdx.x;
    const int gid = blockIdx.x * 256 + tid;
    if (gid < WT) Wbf[gid] = f2bf(W[gid]);       // fold W->bf16 conversion

    __shared__ unsigned short lcol[CHUNK], lrow[CHUNK], lw[CHUNK];
    __shared__ unsigned short sidx[CHUNK];
    __shared__ int hist[256], lofs[256], fill[256], gbase[256];

    const int e0  = blockIdx.x * CHUNK;
    const int cnt = min(CHUNK, E - e0);
    if (cnt <= 0) return;

    hist[tid] = 0; fill[tid] = 0;
    __syncthreads();

    for (int i = tid; i < cnt; i += 256) {
        const int c = cols[e0 + i];
        const int r = rows[e0 + i];
        float w = ew[e0 + i];
        w = (w > 0.0f) ? w : 1e-7f;              // elu(w)<=0 <=> w<=0
        lcol[i] = (unsigned short)c;
        lrow[i] = (unsigned short)r;
        lw[i]   = f2bf(w);
        atomicAdd(&hist[c >> 8], 1);
    }
    __syncthreads();

    // exclusive scan of hist -> lofs
    {
        const int v = hist[tid];
        lofs[tid] = v;
        __syncthreads();
        for (int off = 1; off < 256; off <<= 1) {
            int t = (tid >= off) ? lofs[tid - off] : 0;
            __syncthreads();
            lofs[tid] += t;
            __syncthreads();
        }
        const int excl = lofs[tid] - v;
        __syncthreads();
        lofs[tid] = excl;
        __syncthreads();
    }

    // rank within block -> sorted index
    for (int i = tid; i < cnt; i += 256) {
        const int b = lcol[i] >> 8;
        const int pos = lofs[b] + atomicAdd(&fill[b], 1);
        sidx[pos] = (unsigned short)i;
    }
    __syncthreads();

    // reserve global space: one atomic per non-empty bucket
    {
        const int h = hist[tid];
        gbase[tid] = (h > 0) ? atomicAdd(&tails[tid], h) : 0;
    }
    __syncthreads();

    // write out in bucket-sorted order (runs of consecutive addresses)
    for (int i = tid; i < cnt; i += 256) {
        const int e = sidx[i];
        const int b = lcol[e] >> 8;
        const int slot = gbase[b] + (i - lofs[b]);
        if (slot < CAP) {                         // overflow guard
            const int addr = b * CAP + slot;
            bwr[addr] = ((unsigned int)lw[e] << 16) | lrow[e];
            bcl[addr] = (unsigned char)(lcol[e] & 255);
        }
    }
}

// ---- passB: per-bucket LDS sort + dis/starts/ends; coalesced meta write ----
__global__ __launch_bounds__(256) void k_passB(
    const unsigned int* __restrict__ bwr, const unsigned char* __restrict__ bcl,
    const int* __restrict__ tails,
    unsigned int* __restrict__ meta, int* __restrict__ starts,
    int* __restrict__ ends, float* __restrict__ dis, int N)
{
    const int tid  = threadIdx.x;
    const int b    = blockIdx.x;
    const int base = b * CAP;
    const int cnt  = min(tails[b], CAP);

    __shared__ unsigned int  lwr[CAP];      // 32 KB
    __shared__ unsigned char lcl[CAP];      // 8 KB
    __shared__ unsigned int  srt[CAP];      // 32 KB
    __shared__ int hist[256], offs[256], fill[256];

    hist[tid] = 0; fill[tid] = 0;
    __syncthreads();

    for (int i = tid; i < cnt; i += 256) {
        lwr[i] = bwr[base + i];
        unsigned char c = bcl[base + i];
        lcl[i] = c;
        atomicAdd(&hist[c], 1);
    }
    __syncthreads();

    // exclusive scan of hist -> offs
    {
        const int v = hist[tid];
        offs[tid] = v;
        __syncthreads();
        for (int off = 1; off < 256; off <<= 1) {
            int t = (tid >= off) ? offs[tid - off] : 0;
            __syncthreads();
            offs[tid] += t;
            __syncthreads();
        }
        const int excl = offs[tid] - v;
        __syncthreads();
        offs[tid] = excl;
        __syncthreads();
    }

    // scatter to sorted order (LDS -> LDS)
    for (int i = tid; i < cnt; i += 256) {
        const int c = lcl[i];
        const int pos = offs[c] + atomicAdd(&fill[c], 1);
        srt[pos] = lwr[i];
    }
    __syncthreads();

    // coalesced meta write
    for (int i = tid; i < cnt; i += 256) meta[base + i] = srt[i];

    // per-node: dis = rsqrt(1 + sum w), starts/ends
    const int node = b * BK + tid;
    if (node < N) {
        const int s = offs[tid];
        const int t = s + hist[tid];
        float sum = 1.0f;                         // self-loop
        for (int j = s; j < t; ++j) sum += bf_hi(srt[j]);
        dis[node]    = rsqrtf(sum);
        starts[node] = base + s;
        ends[node]   = base + t;
    }
}

// ---- z[n][:] = bf16( dis[n] * (x[n] @ W^T) ), NATURAL layout, via y^T=Wx^T
__global__ __launch_bounds__(256) void k_transform_mfma(
    const float* __restrict__ x, const unsigned short* __restrict__ Wbf,
    const float* __restrict__ dis, unsigned int* __restrict__ z, int N)
{
    constexpr int RB = 32;
    __shared__ float xs[RB][256];       // 32 KB, LINEAR (global_load_lds dest)

    const int tid  = threadIdx.x;
    const int r0   = blockIdx.x * RB;
    const int hb   = blockIdx.y;        // 0/1: feature half (64 each)
    const int wave = tid >> 6;          // 0..3
    const int lane = tid & 63;
    const int lr   = lane & 15;
    const int kg   = lane >> 4;         // k-group (8 consecutive k each)
    const int wrow = hb * 64 + wave * 16 + lr;   // this lane's W row (A-row)

    // ---- async stage: wave w stages rows 8w..8w+7, 1 KB per instruction.
#pragma unroll
    for (int r = 0; r < 8; ++r) {
        const int row  = wave * 8 + r;
        const int grow = r0 + row;
        if (grow < N) {
            const char* src = (const char*)(x + (size_t)grow * 256)
                              + ((lane * 16) ^ ((row & 7) << 4));
            async_load16(src, &xs[row][0]);
        } else {
            *(float4*)((char*)&xs[row][0] + lane * 16) =
                make_float4(0.f, 0.f, 0.f, 0.f);
        }
    }

    // ---- W frags: 8 distinct addresses for the whole wave lifetime ----
    short8_t wf[8];
#pragma unroll
    for (int k = 0; k < 8; ++k)
        wf[k] = *reinterpret_cast<const short8_t*>(
            Wbf + (size_t)wrow * 256 + k * 32 + kg * 8);

    __syncthreads();   // drains vmcnt(0): staging (+W) complete

    const char* xb = (const char*)&xs[0][0];

#pragma unroll
    for (int xt = 0; xt < 2; ++xt) {
        f32x4_t acc = (f32x4_t){0.f, 0.f, 0.f, 0.f};
        const int xrow = xt * 16 + lr;          // B-col (node within block)
        const int sw   = (xrow & 7) << 4;
#pragma unroll
        for (int k = 0; k < 8; ++k) {
            const int g  = k * 128 + kg * 32;
            const int a0 = xrow * 1024 + (g ^ sw);
            const int a1 = xrow * 1024 + ((g + 16) ^ sw);
            float4 f0 = *(const float4*)(xb + a0);
            float4 f1 = *(const float4*)(xb + a1);
            short8_t bf;
            bf[0] = (short)f2bf(f0.x); bf[1] = (short)f2bf(f0.y);
            bf[2] = (short)f2bf(f0.z); bf[3] = (short)f2bf(f0.w);
            bf[4] = (short)f2bf(f1.x); bf[5] = (short)f2bf(f1.y);
            bf[6] = (short)f2bf(f1.z); bf[7] = (short)f2bf(f1.w);
            acc = __builtin_amdgcn_mfma_f32_16x16x32_bf16(wf[k], bf, acc, 0, 0, 0);
        }
        const int node = r0 + xrow;
        if (node < N) {
            const float d = dis[node];
            unsigned int lo = (unsigned int)f2bf(d * acc[0]) |
                              ((unsigned int)f2bf(d * acc[1]) << 16);
            unsigned int hi = (unsigned int)f2bf(d * acc[2]) |
                              ((unsigned int)f2bf(d * acc[3]) << 16);
            *(uint2*)(&z[(size_t)node * 64 + hb * 32 + wave * 8 + kg * 2]) =
                make_uint2(lo, hi);
        }
    }
}

// ---- hop: one wave per dst node; 16-deep MLP + 8-exact + masked-8 tail ----
// z natural layout: u32 q holds features {2q, 2q+1}. FINAL: float2 store.
template <bool FINAL>
__global__ __launch_bounds__(256) void k_hop(
    const int* __restrict__ starts, const int* __restrict__ ends,
    const unsigned int* __restrict__ meta,
    const float* __restrict__ dis, const unsigned int* __restrict__ hin,
    const float* __restrict__ bias, void* __restrict__ hout, int N)
{
    const int wave = threadIdx.x >> 6;
    const int lane = threadIdx.x & 63;
    const int node = blockIdx.x * 4 + wave;
    if (node >= N) return;

    const int s = __builtin_amdgcn_readfirstlane(starts[node]);
    const int t = __builtin_amdgcn_readfirstlane(ends[node]);
    const float d = dis[node];

    unsigned int v = hin[(size_t)node * 64 + lane];
    float ax0 = bf_lo(v), ay0 = bf_hi(v);          // self term z[c]
    float ax1 = 0.f,      ay1 = 0.f;

    int j = s;
    // 16 outstanding gathers per trip; dual accumulators break FMA chain
    for (; j + 16 <= t; j += 16) {
        unsigned int mm[16];
#pragma unroll
        for (int u = 0; u < 16; ++u) mm[u] = meta[j + u];
        unsigned int uu[16];
#pragma unroll
        for (int u = 0; u < 16; ++u)
            uu[u] = hin[(size_t)(mm[u] & 0xffffu) * 64 + lane];
#pragma unroll
        for (int u = 0; u < 16; u += 2) {
            const float w0 = bf_hi(mm[u]);
            const float w1 = bf_hi(mm[u + 1]);
            ax0 += w0 * bf_lo(uu[u]);     ay0 += w0 * bf_hi(uu[u]);
            ax1 += w1 * bf_lo(uu[u + 1]); ay1 += w1 * bf_hi(uu[u + 1]);
        }
    }
    if (j + 8 <= t) {                    // one exact 8-batch
        unsigned int mm[8];
#pragma unroll
        for (int u = 0; u < 8; ++u) mm[u] = meta[j + u];
        unsigned int uu[8];
#pragma unroll
        for (int u = 0; u < 8; ++u)
            uu[u] = hin[(size_t)(mm[u] & 0xffffu) * 64 + lane];
#pragma unroll
        for (int u = 0; u < 8; u += 2) {
            const float w0 = bf_hi(mm[u]);
            const float w1 = bf_hi(mm[u + 1]);
            ax0 += w0 * bf_lo(uu[u]);     ay0 += w0 * bf_hi(uu[u]);
            ax1 += w1 * bf_lo(uu[u + 1]); ay1 += w1 * bf_hi(uu[u + 1]);
        }
        j += 8;
    }
    if (j < t) {                          // remainder: ONE masked batch
        unsigned int mm[8];
        float        ww[8];
#pragma unroll
        for (int u = 0; u < 8; ++u) {
            const int jj = j + u;
            mm[u] = meta[(jj < t) ? jj : (t - 1)];
            ww[u] = (jj < t) ? bf_hi(mm[u]) : 0.0f;
        }
        unsigned int uu[8];
#pragma unroll
        for (int u = 0; u < 8; ++u)
            uu[u] = hin[(size_t)(mm[u] & 0xffffu) * 64 + lane];
#pragma unroll
        for (int u = 0; u < 8; u += 2) {
            ax0 += ww[u] * bf_lo(uu[u]);         ay0 += ww[u] * bf_hi(uu[u]);
            ax1 += ww[u + 1] * bf_lo(uu[u + 1]); ay1 += ww[u + 1] * bf_hi(uu[u + 1]);
        }
    }

    const float ax = ax0 + ax1;
    const float ay = ay0 + ay1;

    if (FINAL) {
        float2 bv = reinterpret_cast<const float2*>(bias)[lane];
        float2 o; o.x = d * ax + bv.x; o.y = d * ay + bv.y;
        reinterpret_cast<float2*>(hout)[(size_t)node * 64 + lane] = o;
    } else {
        const float d2 = d * d;
        unsigned int p = (unsigned int)f2bf(d2 * ax) |
                         ((unsigned int)f2bf(d2 * ay) << 16);
        reinterpret_cast<unsigned int*>(hout)[(size_t)node * 64 + lane] = p;
    }
}

extern "C" void kernel_launch(void* const* d_in, const int* in_sizes, int n_in,
                              void* d_out, int out_size, void* d_ws, size_t ws_size,
                              hipStream_t stream)
{
    const float* x  = (const float*)d_in[0];
    const int*   ei = (const int*)d_in[1];     // int32 (harness converts)
    const float* ew = (const float*)d_in[2];
    const float* W  = (const float*)d_in[3];
    const float* b  = (const float*)d_in[4];

    const int E  = in_sizes[2];
    const int H  = in_sizes[4];        // 128
    const int T  = in_sizes[3] / H;    // 256
    const int N  = in_sizes[0] / T;    // 50000  (< 65536: 16-bit ids valid)
    const int WT = in_sizes[3];        // 32768
    const int NB = (N + BK - 1) / BK;  // 196 buckets

    const int* rows = ei;              // sources
    const int* cols = ei + E;          // targets (aggregation index)

    // ---- workspace ----
    char* wsb = (char*)d_ws;
    unsigned int*   z    = (unsigned int*)wsb;   wsb += (size_t)N * (H / 2) * 4;  // 12.8 MB
    unsigned int*   z1   = (unsigned int*)wsb;   wsb += (size_t)N * (H / 2) * 4;  // 12.8 MB
    unsigned int*   meta = (unsigned int*)wsb;   wsb += (size_t)NB * CAP * 4;     // 6.4 MB
    unsigned short* Wbf  = (unsigned short*)wsb; wsb += (size_t)WT * 2;           // 64 KB
    float*          dis  = (float*)wsb;          wsb += (size_t)N * 4;
    int*            sta  = (int*)wsb;            wsb += (size_t)N * 4;
    int*            end_ = (int*)wsb;            wsb += (size_t)N * 4;
    int*            tails= (int*)wsb;            wsb += (size_t)NB * 4;
    // bucket staging aliases z1 (dead until hop1 output): bwr 6.4MB + bcl 1.6MB
    unsigned int*   bwr  = z1;                                  // NB*CAP*4
    unsigned char*  bcl  = (unsigned char*)(z1 + (size_t)NB * CAP);

    float* out = (float*)d_out;

    // CSR build: bucket two-pass
    k_zero<<<(NB + 255) / 256, 256, 0, stream>>>(tails, NB);
    {
        const int nblkA = (E + CHUNK - 1) / CHUNK;   // 196 (covers WT too)
        k_passA<<<nblkA, 256, 0, stream>>>(rows, cols, ew, E,
                                           bwr, bcl, tails, W, Wbf, WT);
        k_passB<<<NB, 256, 0, stream>>>(bwr, bcl, tails,
                                        meta, sta, end_, dis, N);
    }

    // transform: z = bf16(dis * (X W^T)), natural layout, y^T = W x^T
    {
        const int RB = 32;
        dim3 grid((N + RB - 1) / RB, 2);
        k_transform_mfma<<<grid, 256, 0, stream>>>(x, Wbf, dis, z, N);
    }

    // hops (hop1 overwrites z1 -> bucket staging dead by then)
    const int gH = (N + 3) / 4;
    k_hop<false><<<gH, 256, 0, stream>>>(sta, end_, meta, dis, z, nullptr, z1, N);
    k_hop<true ><<<gH, 256, 0, stream>>>(sta, end_, meta, dis, z1, b, out, N);
}

// Round 22
// 119.755 us; speedup vs baseline: 1.4324x; 1.0092x over previous
//
#include <hip/hip_runtime.h>

// ---------------------------------------------------------------------------
// SGConv (K=2): out = A^2 (X W^T) + b,  A = D^{-1/2}(Adj_clamped + I)D^{-1/2}
// N=50000, E=800000, T=256, H=128. edge_index arrives as int32.
//
// r22 = r21 + compile fix: nontemporal store via native ext_vector float2
// (clang builtin rejects HIP_vector_type). Everything else identical.
// ---------------------------------------------------------------------------

typedef __attribute__((ext_vector_type(8))) short short8_t;   // 8 bf16
typedef __attribute__((ext_vector_type(4))) float f32x4_t;    // MFMA acc
typedef __attribute__((ext_vector_type(2))) float f32x2_t;    // native float2

constexpr int BK    = 256;   // nodes per bucket
constexpr int CAP   = 8192;  // records per bucket (mean 4096 + 64 sigma)
constexpr int CHUNK = 4096;  // edges per passA block

__device__ inline unsigned short f2bf(float f) {               // RNE f32->bf16
    unsigned int u = __float_as_uint(f);
    return (unsigned short)((u + 0x7fffu + ((u >> 16) & 1u)) >> 16);
}
__device__ inline float bf_lo(unsigned int u) { return __uint_as_float(u << 16); }
__device__ inline float bf_hi(unsigned int u) { return __uint_as_float(u & 0xffff0000u); }

// async 16B/lane global->LDS (wave-uniform LDS base + lane*16)
__device__ inline void async_load16(const void* g, void* l) {
    __builtin_amdgcn_global_load_lds(
        (const __attribute__((address_space(1))) unsigned int*)g,
        (__attribute__((address_space(3))) unsigned int*)l, 16, 0, 0);
}

// ---- zero the bucket tails ----
__global__ __launch_bounds__(256) void k_zero(int* __restrict__ p, int n)
{
    int i = blockIdx.x * 256 + threadIdx.x;
    if (i < n) p[i] = 0;
}

// ---- passA: bucket-bin edges; coalesced appends to bucket storage ----
__global__ __launch_bounds__(256) void k_passA(
    const int* __restrict__ rows, const int* __restrict__ cols,
    const float* __restrict__ ew, int E,
    unsigned int* __restrict__ bwr,   // [NB*CAP]  w<<16|row
    unsigned char* __restrict__ bcl,  // [NB*CAP]  col low byte
    int* __restrict__ tails,          // [NB]
    const float* __restrict__ W, unsigned short* __restrict__ Wbf, int WT)
{
    const int tid = threadIdx.x;
    const int gid = blockIdx.x * 256 + tid;
    if (gid < WT) Wbf[gid] = f2bf(W[gid]);       // fold W->bf16 conversion

    __shared__ unsigned short lcol[CHUNK], lrow[CHUNK], lw[CHUNK];
    __shared__ unsigned short sidx[CHUNK];
    __shared__ int hist[256], lofs[256], fill[256], gbase[256];

    const int e0  = blockIdx.x * CHUNK;
    const int cnt = min(CHUNK, E - e0);
    if (cnt <= 0) return;

    hist[tid] = 0; fill[tid] = 0;
    __syncthreads();

    for (int i = tid; i < cnt; i += 256) {
        const int c = cols[e0 + i];
        const int r = rows[e0 + i];
        float w = ew[e0 + i];
        w = (w > 0.0f) ? w : 1e-7f;              // elu(w)<=0 <=> w<=0
        lcol[i] = (unsigned short)c;
        lrow[i] = (unsigned short)r;
        lw[i]   = f2bf(w);
        atomicAdd(&hist[c >> 8], 1);
    }
    __syncthreads();

    // exclusive scan of hist -> lofs
    {
        const int v = hist[tid];
        lofs[tid] = v;
        __syncthreads();
        for (int off = 1; off < 256; off <<= 1) {
            int t = (tid >= off) ? lofs[tid - off] : 0;
            __syncthreads();
            lofs[tid] += t;
            __syncthreads();
        }
        const int excl = lofs[tid] - v;
        __syncthreads();
        lofs[tid] = excl;
        __syncthreads();
    }

    // rank within block -> sorted index
    for (int i = tid; i < cnt; i += 256) {
        const int b = lcol[i] >> 8;
        const int pos = lofs[b] + atomicAdd(&fill[b], 1);
        sidx[pos] = (unsigned short)i;
    }
    __syncthreads();

    // reserve global space: one atomic per non-empty bucket
    {
        const int h = hist[tid];
        gbase[tid] = (h > 0) ? atomicAdd(&tails[tid], h) : 0;
    }
    __syncthreads();

    // write out in bucket-sorted order (runs of consecutive addresses)
    for (int i = tid; i < cnt; i += 256) {
        const int e = sidx[i];
        const int b = lcol[e] >> 8;
        const int slot = gbase[b] + (i - lofs[b]);
        if (slot < CAP) {                         // overflow guard
            const int addr = b * CAP + slot;
            bwr[addr] = ((unsigned int)lw[e] << 16) | lrow[e];
            bcl[addr] = (unsigned char)(lcol[e] & 255);
        }
    }
}

// ---- passB: per-bucket LDS sort + dis/starts/ends; coalesced meta write ----
__global__ __launch_bounds__(256) void k_passB(
    const unsigned int* __restrict__ bwr, const unsigned char* __restrict__ bcl,
    const int* __restrict__ tails,
    unsigned int* __restrict__ meta, int* __restrict__ starts,
    int* __restrict__ ends, float* __restrict__ dis, int N)
{
    const int tid  = threadIdx.x;
    const int b    = blockIdx.x;
    const int base = b * CAP;
    const int cnt  = min(tails[b], CAP);

    __shared__ unsigned int  lwr[CAP];      // 32 KB
    __shared__ unsigned char lcl[CAP];      // 8 KB
    __shared__ unsigned int  srt[CAP];      // 32 KB
    __shared__ int hist[256], offs[256], fill[256];

    hist[tid] = 0; fill[tid] = 0;
    __syncthreads();

    for (int i = tid; i < cnt; i += 256) {
        lwr[i] = bwr[base + i];
        unsigned char c = bcl[base + i];
        lcl[i] = c;
        atomicAdd(&hist[c], 1);
    }
    __syncthreads();

    // exclusive scan of hist -> offs
    {
        const int v = hist[tid];
        offs[tid] = v;
        __syncthreads();
        for (int off = 1; off < 256; off <<= 1) {
            int t = (tid >= off) ? offs[tid - off] : 0;
            __syncthreads();
            offs[tid] += t;
            __syncthreads();
        }
        const int excl = offs[tid] - v;
        __syncthreads();
        offs[tid] = excl;
        __syncthreads();
    }

    // scatter to sorted order (LDS -> LDS)
    for (int i = tid; i < cnt; i += 256) {
        const int c = lcl[i];
        const int pos = offs[c] + atomicAdd(&fill[c], 1);
        srt[pos] = lwr[i];
    }
    __syncthreads();

    // coalesced meta write
    for (int i = tid; i < cnt; i += 256) meta[base + i] = srt[i];

    // per-node: dis = rsqrt(1 + sum w), starts/ends
    const int node = b * BK + tid;
    if (node < N) {
        const int s = offs[tid];
        const int t = s + hist[tid];
        float sum = 1.0f;                         // self-loop
        for (int j = s; j < t; ++j) sum += bf_hi(srt[j]);
        dis[node]    = rsqrtf(sum);
        starts[node] = base + s;
        ends[node]   = base + t;
    }
}

// ---- z[n][:] = bf16( dis[n] * (x[n] @ W^T) ), NATURAL layout, via y^T=Wx^T
__global__ __launch_bounds__(256) void k_transform_mfma(
    const float* __restrict__ x, const unsigned short* __restrict__ Wbf,
    const float* __restrict__ dis, unsigned int* __restrict__ z, int N)
{
    constexpr int RB = 32;
    __shared__ float xs[RB][256];       // 32 KB, LINEAR (global_load_lds dest)

    const int tid  = threadIdx.x;
    const int r0   = blockIdx.x * RB;
    const int hb   = blockIdx.y;        // 0/1: feature half (64 each)
    const int wave = tid >> 6;          // 0..3
    const int lane = tid & 63;
    const int lr   = lane & 15;
    const int kg   = lane >> 4;         // k-group (8 consecutive k each)
    const int wrow = hb * 64 + wave * 16 + lr;   // this lane's W row (A-row)

    // ---- async stage: wave w stages rows 8w..8w+7, 1 KB per instruction.
#pragma unroll
    for (int r = 0; r < 8; ++r) {
        const int row  = wave * 8 + r;
        const int grow = r0 + row;
        if (grow < N) {
            const char* src = (const char*)(x + (size_t)grow * 256)
                              + ((lane * 16) ^ ((row & 7) << 4));
            async_load16(src, &xs[row][0]);
        } else {
            *(float4*)((char*)&xs[row][0] + lane * 16) =
                make_float4(0.f, 0.f, 0.f, 0.f);
        }
    }

    // ---- W frags: 8 distinct addresses for the whole wave lifetime ----
    short8_t wf[8];
#pragma unroll
    for (int k = 0; k < 8; ++k)
        wf[k] = *reinterpret_cast<const short8_t*>(
            Wbf + (size_t)wrow * 256 + k * 32 + kg * 8);

    __syncthreads();   // drains vmcnt(0): staging (+W) complete

    const char* xb = (const char*)&xs[0][0];

#pragma unroll
    for (int xt = 0; xt < 2; ++xt) {
        f32x4_t acc = (f32x4_t){0.f, 0.f, 0.f, 0.f};
        const int xrow = xt * 16 + lr;          // B-col (node within block)
        const int sw   = (xrow & 7) << 4;
#pragma unroll
        for (int k = 0; k < 8; ++k) {
            const int g  = k * 128 + kg * 32;
            const int a0 = xrow * 1024 + (g ^ sw);
            const int a1 = xrow * 1024 + ((g + 16) ^ sw);
            float4 f0 = *(const float4*)(xb + a0);
            float4 f1 = *(const float4*)(xb + a1);
            short8_t bf;
            bf[0] = (short)f2bf(f0.x); bf[1] = (short)f2bf(f0.y);
            bf[2] = (short)f2bf(f0.z); bf[3] = (short)f2bf(f0.w);
            bf[4] = (short)f2bf(f1.x); bf[5] = (short)f2bf(f1.y);
            bf[6] = (short)f2bf(f1.z); bf[7] = (short)f2bf(f1.w);
            acc = __builtin_amdgcn_mfma_f32_16x16x32_bf16(wf[k], bf, acc, 0, 0, 0);
        }
        const int node = r0 + xrow;
        if (node < N) {
            const float d = dis[node];
            unsigned int lo = (unsigned int)f2bf(d * acc[0]) |
                              ((unsigned int)f2bf(d * acc[1]) << 16);
            unsigned int hi = (unsigned int)f2bf(d * acc[2]) |
                              ((unsigned int)f2bf(d * acc[3]) << 16);
            *(uint2*)(&z[(size_t)node * 64 + hb * 32 + wave * 8 + kg * 2]) =
                make_uint2(lo, hi);
        }
    }
}

// ---- hop: one wave per dst node; 16-deep MLP; nontemporal meta/out ----
// z natural layout: u32 q holds features {2q, 2q+1}. FINAL: float2 store.
template <bool FINAL>
__global__ __launch_bounds__(256) void k_hop(
    const int* __restrict__ starts, const int* __restrict__ ends,
    const unsigned int* __restrict__ meta,
    const float* __restrict__ dis, const unsigned int* __restrict__ hin,
    const float* __restrict__ bias, void* __restrict__ hout, int N)
{
    const int wave = threadIdx.x >> 6;
    const int lane = threadIdx.x & 63;
    const int node = blockIdx.x * 4 + wave;
    if (node >= N) return;

    const int s = __builtin_amdgcn_readfirstlane(starts[node]);
    const int t = __builtin_amdgcn_readfirstlane(ends[node]);
    const float d = dis[node];

    unsigned int v = hin[(size_t)node * 64 + lane];
    float ax0 = bf_lo(v), ay0 = bf_hi(v);          // self term z[c]
    float ax1 = 0.f,      ay1 = 0.f;

    int j = s;
    // 16 outstanding gathers per trip; dual accumulators break FMA chain
    for (; j + 16 <= t; j += 16) {
        unsigned int mm[16];
#pragma unroll
        for (int u = 0; u < 16; ++u)
            mm[u] = __builtin_nontemporal_load(&meta[j + u]);
        unsigned int uu[16];
#pragma unroll
        for (int u = 0; u < 16; ++u)
            uu[u] = hin[(size_t)(mm[u] & 0xffffu) * 64 + lane];
#pragma unroll
        for (int u = 0; u < 16; u += 2) {
            const float w0 = bf_hi(mm[u]);
            const float w1 = bf_hi(mm[u + 1]);
            ax0 += w0 * bf_lo(uu[u]);     ay0 += w0 * bf_hi(uu[u]);
            ax1 += w1 * bf_lo(uu[u + 1]); ay1 += w1 * bf_hi(uu[u + 1]);
        }
    }
    if (j + 8 <= t) {                    // one exact 8-batch
        unsigned int mm[8];
#pragma unroll
        for (int u = 0; u < 8; ++u)
            mm[u] = __builtin_nontemporal_load(&meta[j + u]);
        unsigned int uu[8];
#pragma unroll
        for (int u = 0; u < 8; ++u)
            uu[u] = hin[(size_t)(mm[u] & 0xffffu) * 64 + lane];
#pragma unroll
        for (int u = 0; u < 8; u += 2) {
            const float w0 = bf_hi(mm[u]);
            const float w1 = bf_hi(mm[u + 1]);
            ax0 += w0 * bf_lo(uu[u]);     ay0 += w0 * bf_hi(uu[u]);
            ax1 += w1 * bf_lo(uu[u + 1]); ay1 += w1 * bf_hi(uu[u + 1]);
        }
        j += 8;
    }
    if (j < t) {                          // remainder: ONE masked batch
        unsigned int mm[8];
        float        ww[8];
#pragma unroll
        for (int u = 0; u < 8; ++u) {
            const int jj = j + u;
            mm[u] = __builtin_nontemporal_load(&meta[(jj < t) ? jj : (t - 1)]);
            ww[u] = (jj < t) ? bf_hi(mm[u]) : 0.0f;
        }
        unsigned int uu[8];
#pragma unroll
        for (int u = 0; u < 8; ++u)
            uu[u] = hin[(size_t)(mm[u] & 0xffffu) * 64 + lane];
#pragma unroll
        for (int u = 0; u < 8; u += 2) {
            ax0 += ww[u] * bf_lo(uu[u]);         ay0 += ww[u] * bf_hi(uu[u]);
            ax1 += ww[u + 1] * bf_lo(uu[u + 1]); ay1 += ww[u + 1] * bf_hi(uu[u + 1]);
        }
    }

    const float ax = ax0 + ax1;
    const float ay = ay0 + ay1;

    if (FINAL) {
        float2 bv = reinterpret_cast<const float2*>(bias)[lane];
        f32x2_t o;                         // native vector: builtin-compatible
        o.x = d * ax + bv.x;
        o.y = d * ay + bv.y;
        // final output is never re-read: don't pollute L2
        __builtin_nontemporal_store(
            o, reinterpret_cast<f32x2_t*>(hout) + (size_t)node * 64 + lane);
    } else {
        const float d2 = d * d;
        unsigned int p = (unsigned int)f2bf(d2 * ax) |
                         ((unsigned int)f2bf(d2 * ay) << 16);
        reinterpret_cast<unsigned int*>(hout)[(size_t)node * 64 + lane] = p;
    }
}

extern "C" void kernel_launch(void* const* d_in, const int* in_sizes, int n_in,
                              void* d_out, int out_size, void* d_ws, size_t ws_size,
                              hipStream_t stream)
{
    const float* x  = (const float*)d_in[0];
    const int*   ei = (const int*)d_in[1];     // int32 (harness converts)
    const float* ew = (const float*)d_in[2];
    const float* W  = (const float*)d_in[3];
    const float* b  = (const float*)d_in[4];

    const int E  = in_sizes[2];
    const int H  = in_sizes[4];        // 128
    const int T  = in_sizes[3] / H;    // 256
    const int N  = in_sizes[0] / T;    // 50000  (< 65536: 16-bit ids valid)
    const int WT = in_sizes[3];        // 32768
    const int NB = (N + BK - 1) / BK;  // 196 buckets

    const int* rows = ei;              // sources
    const int* cols = ei + E;          // targets (aggregation index)

    // ---- workspace ----
    char* wsb = (char*)d_ws;
    unsigned int*   z    = (unsigned int*)wsb;   wsb += (size_t)N * (H / 2) * 4;  // 12.8 MB
    unsigned int*   z1   = (unsigned int*)wsb;   wsb += (size_t)N * (H / 2) * 4;  // 12.8 MB
    unsigned int*   meta = (unsigned int*)wsb;   wsb += (size_t)NB * CAP * 4;     // 6.4 MB
    unsigned short* Wbf  = (unsigned short*)wsb; wsb += (size_t)WT * 2;           // 64 KB
    float*          dis  = (float*)wsb;          wsb += (size_t)N * 4;
    int*            sta  = (int*)wsb;            wsb += (size_t)N * 4;
    int*            end_ = (int*)wsb;            wsb += (size_t)N * 4;
    int*            tails= (int*)wsb;            wsb += (size_t)NB * 4;
    // bucket staging aliases z1 (dead until hop1 output): bwr 6.4MB + bcl 1.6MB
    unsigned int*   bwr  = z1;                                  // NB*CAP*4
    unsigned char*  bcl  = (unsigned char*)(z1 + (size_t)NB * CAP);

    float* out = (float*)d_out;

    // CSR build: bucket two-pass
    k_zero<<<(NB + 255) / 256, 256, 0, stream>>>(tails, NB);
    {
        const int nblkA = (E + CHUNK - 1) / CHUNK;   // 196 (covers WT too)
        k_passA<<<nblkA, 256, 0, stream>>>(rows, cols, ew, E,
                                           bwr, bcl, tails, W, Wbf, WT);
        k_passB<<<NB, 256, 0, stream>>>(bwr, bcl, tails,
                                        meta, sta, end_, dis, N);
    }

    // transform: z = bf16(dis * (X W^T)), natural layout, y^T = W x^T
    {
        const int RB = 32;
        dim3 grid((N + RB - 1) / RB, 2);
        k_transform_mfma<<<grid, 256, 0, stream>>>(x, Wbf, dis, z, N);
    }

    // hops (hop1 overwrites z1 -> bucket staging dead by then)
    const int gH = (N + 3) / 4;
    k_hop<false><<<gH, 256, 0, stream>>>(sta, end_, meta, dis, z, nullptr, z1, N);
    k_hop<true ><<<gH, 256, 0, stream>>>(sta, end_, meta, dis, z1, b, out, N);
}